// Round 1
// baseline (337.988 us; speedup 1.0000x reference)
//
#include <hip/hip_runtime.h>

#define SEQ   512
#define BATCH 256
#define DIN   128
#define HID   256
#define CHUNK 8
#define NOISE 0.99f

__device__ __forceinline__ float dot4(float4 a, float4 b) {
    return fmaf(a.x, b.x, fmaf(a.y, b.y, fmaf(a.z, b.z, a.w * b.w)));
}
__device__ __forceinline__ float sigmoid_(float x) {
    return 1.0f / (1.0f + __expf(-x));
}
__device__ __forceinline__ float tanh_(float x) {
    float ax = fabsf(x);
    float e  = __expf(2.0f * ax);
    float r  = 1.0f - 2.0f / (e + 1.0f);   // tanh(|x|); safe if e==inf
    return copysignf(r, x);
}

// One block per batch element; persistent over all SEQ steps.
// Thread layout: t = p*16 + j, p = g*4 + q (pair index), j = 16-lane reduction slot.
// Wave w == gate g (lanes 64g..64g+63), so cross-qubit exchange stays in-wave.
__global__ __launch_bounds__(256, 1) void qlstm_kernel(
    const float* __restrict__ x,      // (S, B, D)
    const float* __restrict__ w_lin,  // (4, 4, 384)  [0:128)=x part, [128:384)=h part
    const float* __restrict__ b_lin,  // (4, 4)
    const float* __restrict__ w_map,  // (4, 256, 4)
    const float* __restrict__ b_map,  // (4, 256)
    const float* __restrict__ theta,  // (4, 4)
    float* __restrict__ out)          // S*B*H ++ B*H (hx) ++ B*H (cx)
{
    const int b = blockIdx.x;
    const int t = threadIdx.x;
    const int p = t >> 4;        // 0..15 : gate g = p>>2, qubit q = p&3
    const int j = t & 15;
    const int q = p & 3;
    const int g = p >> 2;

    __shared__ __align__(16) float hx_lds[HID];
    __shared__ __align__(16) float acts_lds[16];
    __shared__ __align__(16) float x_lds[2][CHUNK][DIN];

    // ---- weights for phase 1 (pre = w_lin . [x; hx] + b_lin), held in registers.
    // thread (p,j) covers d = j*4 + 64k + m  (x part k=0..1, h part k=0..3)
    const float* wp = w_lin + p * 384 + j * 4;
    const float4 wx0 = *(const float4*)(wp);
    const float4 wx1 = *(const float4*)(wp + 64);
    const float4 wh0 = *(const float4*)(wp + 128);
    const float4 wh1 = *(const float4*)(wp + 192);
    const float4 wh2 = *(const float4*)(wp + 256);
    const float4 wh3 = *(const float4*)(wp + 320);
    const float blin_p = b_lin[p];
    const float th_p   = theta[p];

    // ---- weights for phase 2 (gates = w_map . acts + b_map), thread t owns h = t.
    const float4 wm0 = ((const float4*)w_map)[0 * 256 + t];
    const float4 wm1 = ((const float4*)w_map)[1 * 256 + t];
    const float4 wm2 = ((const float4*)w_map)[2 * 256 + t];
    const float4 wm3 = ((const float4*)w_map)[3 * 256 + t];
    const float bm0 = b_map[t];
    const float bm1 = b_map[256 + t];
    const float bm2 = b_map[512 + t];
    const float bm3 = b_map[768 + t];

    // ---- x chunk staging: 8 steps (8*128 floats) double-buffered in LDS.
    const int xr = t >> 5;          // row within chunk 0..7
    const int xc = (t & 31) * 4;    // float4 column
    float4 xq;
    xq = *(const float4*)(x + ((size_t)(0 * CHUNK + xr) * BATCH + b) * DIN + xc);
    hx_lds[t] = 0.0f;
    *(float4*)&x_lds[0][xr][xc] = xq;                       // chunk 0 -> buf 0
    xq = *(const float4*)(x + ((size_t)(1 * CHUNK + xr) * BATCH + b) * DIN + xc); // prefetch chunk 1
    __syncthreads();

    float hx = 0.0f, cx = 0.0f;
    float* out_seq = out;
    float* out_hx  = out + (size_t)SEQ * BATCH * HID;
    float* out_cx  = out_hx + BATCH * HID;

    for (int s = 0; s < SEQ; ++s) {
        if ((s & (CHUNK - 1)) == 0 && s > 0) {
            const int c = s >> 3;
            *(float4*)&x_lds[c & 1][xr][xc] = xq;           // commit prefetched chunk c
            if (s + CHUNK < SEQ)
                xq = *(const float4*)(x + ((size_t)(s + CHUNK + xr) * BATCH + b) * DIN + xc);
            __syncthreads();
        }

        // ---------------- phase 1: pre[p], quantum layer, activation --------
        const float* xrow = x_lds[(s >> 3) & 1][s & (CHUNK - 1)];
        const float4 xa0 = *(const float4*)(xrow + j * 4);
        const float4 xa1 = *(const float4*)(xrow + 64 + j * 4);
        const float4 ha0 = *(const float4*)(&hx_lds[j * 4]);
        const float4 ha1 = *(const float4*)(&hx_lds[64 + j * 4]);
        const float4 ha2 = *(const float4*)(&hx_lds[128 + j * 4]);
        const float4 ha3 = *(const float4*)(&hx_lds[192 + j * 4]);

        float acc = dot4(wx0, xa0) + dot4(wx1, xa1)
                  + dot4(wh0, ha0) + dot4(wh1, ha1)
                  + dot4(wh2, ha2) + dot4(wh3, ha3);
        acc += __shfl_xor(acc, 1);
        acc += __shfl_xor(acc, 2);
        acc += __shfl_xor(acc, 4);
        acc += __shfl_xor(acc, 8);

        const float pre = acc + blin_p;
        const float A   = __cosf(pre + th_p);       // C_q of own qubit
        const float Bv  = __shfl_xor(A, 16);        // C_{q^1}
        const float Cv  = __shfl_xor(A, 32);        // C_{q^2}
        const float Dv  = __shfl_xor(Bv, 32);       // C_{q^3}

        // <Z_0>=C1C2C3  <Z_1>=C0C1  <Z_2>=C0C1C2  <Z_3>=C0C1C2C3
        const float t1 = Cv * Dv;                   // C_{q^2} * C_{q^3}
        const float u  = (q & 1) ? (A * Bv) : ((q == 2) ? A : Bv);
        const float v  = (q == 1) ? 1.0f : t1;
        const float ez = NOISE * u * v;

        const float act = (g == 2) ? tanh_(ez) : sigmoid_(ez);  // wave-uniform branch
        if (j == 0) acts_lds[p] = act;
        __syncthreads();                            // B1: acts visible; phase-1 LDS reads done

        // ---------------- phase 2: gate matvec + cell update ----------------
        const float4 a0 = *(const float4*)&acts_lds[0];
        const float4 a1 = *(const float4*)&acts_lds[4];
        const float4 a2 = *(const float4*)&acts_lds[8];
        const float4 a3 = *(const float4*)&acts_lds[12];

        const float fv = bm0 + dot4(wm0, a0);
        const float iv = bm1 + dot4(wm1, a1);
        const float gv = bm2 + dot4(wm2, a2);
        const float ov = bm3 + dot4(wm3, a3);

        cx = fmaf(fv, cx, iv * gv);
        hx = ov * tanh_(cx);

        hx_lds[t] = hx;                             // safe: after B1
        out_seq[((size_t)s * BATCH + b) * HID + t] = hx;
        __syncthreads();                            // B2: hx visible; acts reads done
    }

    out_hx[(size_t)b * HID + t] = hx;
    out_cx[(size_t)b * HID + t] = cx;
}

extern "C" void kernel_launch(void* const* d_in, const int* in_sizes, int n_in,
                              void* d_out, int out_size, void* d_ws, size_t ws_size,
                              hipStream_t stream) {
    const float* x     = (const float*)d_in[0];
    const float* w_lin = (const float*)d_in[1];
    const float* b_lin = (const float*)d_in[2];
    const float* w_map = (const float*)d_in[3];
    const float* b_map = (const float*)d_in[4];
    const float* theta = (const float*)d_in[5];
    qlstm_kernel<<<dim3(BATCH), dim3(256), 0, stream>>>(
        x, w_lin, b_lin, w_map, b_map, theta, (float*)d_out);
}

// Round 2
// 297.301 us; speedup vs baseline: 1.1369x; 1.1369x over previous
//
#include <hip/hip_runtime.h>

#define SEQ   512
#define BATCH 256
#define DIN   128
#define HID   256
#define NOISE 0.99f

__device__ __forceinline__ float dot4(float4 a, float4 b) {
    return fmaf(a.x, b.x, fmaf(a.y, b.y, fmaf(a.z, b.z, a.w * b.w)));
}
__device__ __forceinline__ float sigmoid_(float x) {
    return 1.0f / (1.0f + __expf(-x));
}
__device__ __forceinline__ float tanh_(float x) {
    float ax = fabsf(x);
    float e  = __expf(2.0f * ax);
    float r  = 1.0f - 2.0f / (e + 1.0f);
    return copysignf(r, x);
}

// DPP move: quad_perm / row_ror within 16-lane rows (VALU pipe, ~2 cy)
template <int CTRL>
__device__ __forceinline__ float dppmov(float v) {
    return __int_as_float(__builtin_amdgcn_mov_dpp(__float_as_int(v), CTRL, 0xF, 0xF, false));
}
// xor-16 butterfly sum via gfx950 v_permlane16_swap_b32 (VALU)
__device__ __forceinline__ float swap16_sum(float v) {
    float a = v, b;
    asm("v_mov_b32 %1, %0\n\tv_permlane16_swap_b32 %0, %1" : "+v"(a), "=&v"(b));
    return a + b;   // rows (0,1) and (2,3) pairwise summed -> every lane has lane^16 partner sum
}
// xor-32 butterfly sum via v_permlane32_swap_b32
__device__ __forceinline__ float swap32_sum(float v) {
    float a = v, b;
    asm("v_mov_b32 %1, %0\n\tv_permlane32_swap_b32 %0, %1" : "+v"(a), "=&v"(b));
    return a + b;
}

// ---------------------------------------------------------------------------
// Kernel 1: pre[s,b,p] = b_lin[p] + theta[p] + sum_d w_lin[p,d] * x[s,b,d]
// block: 256 thr = 16 b x 16 p; grid: 512 s x 16 b-tiles
// ---------------------------------------------------------------------------
__global__ __launch_bounds__(256, 2) void pre_gemm(
    const float* __restrict__ x,      // (S,B,D)
    const float* __restrict__ w_lin,  // (16,384) x-part = [0:128)
    const float* __restrict__ b_lin,  // (16,)
    const float* __restrict__ theta,  // (16,)
    float* pre, int pstride)
{
    __shared__ float wlds[16 * 132];  // pad 128->132: p,p+8 share banks (2-way, free)
    const int t = threadIdx.x;
    for (int i = t; i < 16 * 128; i += 256) {
        int pp = i >> 7, dd = i & 127;
        wlds[pp * 132 + dd] = w_lin[pp * 384 + dd];
    }
    __syncthreads();
    const int s = blockIdx.x >> 4;
    const int b = ((blockIdx.x & 15) << 4) + (t >> 4);
    const int p = t & 15;
    const float* xr = x + ((size_t)s * BATCH + b) * DIN;
    const float* wr = &wlds[p * 132];
    float acc = b_lin[p] + theta[p];
    #pragma unroll 8
    for (int d = 0; d < 32; ++d)
        acc += dot4(*(const float4*)(xr + d * 4), *(const float4*)(wr + d * 4));
    pre[((size_t)s * BATCH + b) * pstride + p] = acc;
}

// ---------------------------------------------------------------------------
// Kernel 2: persistent recurrence. 1 block / batch elem, 256 thr (4 waves).
// Lane layout: wave = gate g; l = t&63, q = l&3, j = l>>2 (16 reduction slots
// of 16 hx dims each). All phase-1 comms on the VALU pipe (DPP + permlane).
// ---------------------------------------------------------------------------
__global__ __launch_bounds__(256, 1) void qlstm_rec(
    const float* __restrict__ w_lin,  // (16, 384), hx part = [128:384)
    const float* __restrict__ w_map,  // (4, 256, 4)
    const float* __restrict__ b_map,  // (4, 256)
    const float* pre, int pstride,    // may alias out (no restrict!)
    float* out)
{
    const int b = blockIdx.x;
    const int t = threadIdx.x;
    const int l = t & 63;
    const int g = t >> 6;        // wave index == gate
    const int q = l & 3;
    const int j = l >> 2;        // 0..15
    const int p = (g << 2) | q;

    __shared__ __align__(16) float hx_lds[HID];
    __shared__ __align__(16) float acts_lds[16];

    // hx-part weights; LDS-read slot k returns hx slot (k ^ sig), so load the
    // matching weight slot into register k (swizzle folded into init).
    const int sig = (j >> 1) & 3;
    const float* wp = w_lin + p * 384 + 128 + j * 16;
    const float4 wh0 = *(const float4*)(wp + ((0 ^ sig) << 2));
    const float4 wh1 = *(const float4*)(wp + ((1 ^ sig) << 2));
    const float4 wh2 = *(const float4*)(wp + ((2 ^ sig) << 2));
    const float4 wh3 = *(const float4*)(wp + ((3 ^ sig) << 2));

    // phase-2 weights: thread t owns h = t
    const float4 wm0 = ((const float4*)w_map)[0 * 256 + t];
    const float4 wm1 = ((const float4*)w_map)[1 * 256 + t];
    const float4 wm2 = ((const float4*)w_map)[2 * 256 + t];
    const float4 wm3 = ((const float4*)w_map)[3 * 256 + t];
    const float bm0 = b_map[t];
    const float bm1 = b_map[256 + t];
    const float bm2 = b_map[512 + t];
    const float bm3 = b_map[768 + t];

    // bank-conflict-free hx read addresses (XOR swizzle on the read side)
    const float* hr = &hx_lds[j * 16];
    const float* hr0 = hr + ((0 ^ sig) << 2);
    const float* hr1 = hr + ((1 ^ sig) << 2);
    const float* hr2 = hr + ((2 ^ sig) << 2);
    const float* hr3 = hr + ((3 ^ sig) << 2);

    // pre prefetch: 2 steps ahead (safe vs. the out-row overwrite when aliased)
    const float*  pb      = pre + (size_t)b * pstride + p;
    const size_t  sstride = (size_t)BATCH * pstride;
    float px0 = pb[0];
    float px1 = pb[sstride];

    hx_lds[t] = 0.0f;
    float hx = 0.0f, cx = 0.0f;
    float* out_seq = out;
    float* out_hx  = out + (size_t)SEQ * BATCH * HID;
    float* out_cx  = out_hx + BATCH * HID;
    __syncthreads();

    for (int s = 0; s < SEQ; ++s) {
        const float pxu = px0;
        px0 = px1;
        const int s2 = (s + 2 < SEQ) ? s + 2 : SEQ - 1;
        px1 = pb[(size_t)s2 * sstride];

        // ---- phase 1: hx matvec + reduce (VALU comms) + quantum + act ------
        const float4 ha0 = *(const float4*)hr0;
        const float4 ha1 = *(const float4*)hr1;
        const float4 ha2 = *(const float4*)hr2;
        const float4 ha3 = *(const float4*)hr3;
        float acc = dot4(wh0, ha0) + dot4(wh1, ha1)
                  + dot4(wh2, ha2) + dot4(wh3, ha3);
        acc += dppmov<0x124>(acc);   // row_ror:4  (j bit 0)
        acc += dppmov<0x128>(acc);   // row_ror:8  (j bit 1)
        acc  = swap16_sum(acc);      // j bit 2
        acc  = swap32_sum(acc);      // j bit 3

        const float A  = __cosf(acc + pxu);      // pre includes b_lin + theta
        const float Bv = dppmov<0xB1>(A);        // quad_perm xor1 -> C_{q^1}
        const float Cv = dppmov<0x4E>(A);        // quad_perm xor2 -> C_{q^2}
        const float Dv = dppmov<0x4E>(Bv);       //                -> C_{q^3}

        const float t1 = Cv * Dv;
        const float u  = (q & 1) ? (A * Bv) : ((q == 2) ? A : Bv);
        const float v  = (q == 1) ? 1.0f : t1;
        const float ez = NOISE * u * v;
        const float act = (g == 2) ? tanh_(ez) : sigmoid_(ez);
        if (l < 4) acts_lds[(g << 2) | l] = act;
        __syncthreads();                          // B1: acts visible

        // ---- phase 2: gate matvec + cell update ---------------------------
        const float4 a0 = *(const float4*)&acts_lds[0];
        const float4 a1 = *(const float4*)&acts_lds[4];
        const float4 a2 = *(const float4*)&acts_lds[8];
        const float4 a3 = *(const float4*)&acts_lds[12];

        const float fv = bm0 + dot4(wm0, a0);
        const float iv = bm1 + dot4(wm1, a1);
        const float gv = bm2 + dot4(wm2, a2);
        const float ov = bm3 + dot4(wm3, a3);

        cx = fmaf(fv, cx, iv * gv);
        hx = ov * tanh_(cx);

        hx_lds[t] = hx;
        out_seq[((size_t)s * BATCH + b) * HID + t] = hx;
        __syncthreads();                          // B2: hx visible
    }

    out_hx[(size_t)b * HID + t] = hx;
    out_cx[(size_t)b * HID + t] = cx;
}

extern "C" void kernel_launch(void* const* d_in, const int* in_sizes, int n_in,
                              void* d_out, int out_size, void* d_ws, size_t ws_size,
                              hipStream_t stream) {
    const float* x     = (const float*)d_in[0];
    const float* w_lin = (const float*)d_in[1];
    const float* b_lin = (const float*)d_in[2];
    const float* w_map = (const float*)d_in[3];
    const float* b_map = (const float*)d_in[4];
    const float* theta = (const float*)d_in[5];
    float* out = (float*)d_out;

    const size_t pre_bytes = (size_t)SEQ * BATCH * 16 * sizeof(float);
    float* pre;
    int pstride;
    if (ws_size >= pre_bytes) {          // scratch big enough: clean path
        pre = (float*)d_ws;
        pstride = 16;
    } else {                              // stash pre in the not-yet-written out rows
        pre = out;                        // row s overwritten only at end of step s;
        pstride = HID;                    // reads run 2 steps ahead of the overwrite
    }

    pre_gemm<<<dim3(SEQ * 16), dim3(256), 0, stream>>>(x, w_lin, b_lin, theta, pre, pstride);
    qlstm_rec<<<dim3(BATCH), dim3(256), 0, stream>>>(w_lin, w_map, b_map, pre, pstride, out);
}